// Round 9
// baseline (508.942 us; speedup 1.0000x reference)
//
#include <hip/hip_runtime.h>

#define N_NODES 50000
#define N_EDGES 800000
#define ND 128
#define ED 32
#define AD 128
#define CAT 288   // 2*ND + ED
#define G3 384    // 3*ND

#define XP2 168       // LDS row stride for X=[S(128)|E(32)] (bf16 elems), 16B-aligned
#define SCAN_BS 512

// aux_kernel block partition: agg first (longest), then esum, then converts
#define AGG_B 6250    // 50000 nodes / 8 per block (2 nodes per wave, float4 lanes)
#define ESUM_B 1563   // 50000 nodes / 32 per block (8 lanes x float4 per node)
#define CW_B 288      // 73728 / 256
#define CG_B 768      // 196608 / 256

typedef unsigned short ushort_t;
typedef __attribute__((ext_vector_type(8))) short bfrag;   // 8 bf16 (4 VGPRs)
typedef __attribute__((ext_vector_type(4))) float f32x4;   // MFMA accumulator

__device__ __forceinline__ unsigned int f2bf(float f) {
    unsigned int u = __float_as_uint(f);
    return (u + 0x7FFFu + ((u >> 16) & 1u)) >> 16;   // RTNE to bf16
}
__device__ __forceinline__ void split2(float a, float b,
                                       unsigned int& hi, unsigned int& lo) {
    const unsigned int ha = f2bf(a), hb = f2bf(b);
    const float ra = a - __uint_as_float(ha << 16);
    const float rb = b - __uint_as_float(hb << 16);
    hi = ha | (hb << 16);
    lo = f2bf(ra) | (f2bf(rb) << 16);
}
__device__ __forceinline__ void split1(float a, ushort_t& hi, ushort_t& lo) {
    const unsigned int ha = f2bf(a);
    const float ra = a - __uint_as_float(ha << 16);
    hi = (ushort_t)ha;
    lo = (ushort_t)f2bf(ra);
}
__device__ __forceinline__ float4 f4add(const float4 a, const float4 b) {
    return make_float4(a.x + b.x, a.y + b.y, a.z + b.z, a.w + b.w);
}

// ========================= counting sort by dst ============================
__global__ __launch_bounds__(256) void hist_kernel(
    const int* __restrict__ dst, int* __restrict__ deg)
{
    const int e = blockIdx.x * 256 + threadIdx.x;
    if (e < N_EDGES) atomicAdd(&deg[dst[e]], 1);
}

__global__ __launch_bounds__(SCAN_BS) void scan_block_kernel(
    const int* __restrict__ in, int* __restrict__ out,
    int* __restrict__ bsum, int n)
{
    __shared__ int s[SCAN_BS];
    const int g = blockIdx.x * SCAN_BS + threadIdx.x;
    const int v = (g < n) ? in[g] : 0;
    s[threadIdx.x] = v;
    __syncthreads();
    for (int off = 1; off < SCAN_BS; off <<= 1) {
        const int x = (threadIdx.x >= off) ? s[threadIdx.x - off] : 0;
        __syncthreads();
        s[threadIdx.x] += x;
        __syncthreads();
    }
    if (g < n) out[g] = s[threadIdx.x] - v;   // exclusive
    if (threadIdx.x == SCAN_BS - 1) bsum[blockIdx.x] = s[threadIdx.x];
}

__global__ __launch_bounds__(128) void scan_sums_kernel(int* __restrict__ bsum, int nb)
{
    __shared__ int s[128];
    const int i = threadIdx.x;
    s[i] = (i < nb) ? bsum[i] : 0;
    __syncthreads();
    if (i == 0) {
        int acc = 0;
        for (int k = 0; k < nb; ++k) { const int t = s[k]; s[k] = acc; acc += t; }
    }
    __syncthreads();
    if (i < nb) bsum[i] = s[i];
}

__global__ __launch_bounds__(SCAN_BS) void scan_add_kernel(
    int* __restrict__ rowptr, int* __restrict__ cursor,
    const int* __restrict__ bsum, int n)
{
    const int g = blockIdx.x * SCAN_BS + threadIdx.x;
    if (g < n) {
        const int v = rowptr[g] + bsum[blockIdx.x];
        rowptr[g] = v;
        cursor[g] = v;
    }
}

// fill: ONE 8B aligned random store per edge (was two 4B stores to two
// arrays -> 2 random RMW lines/edge). edat[p] = {perm=e, src[e]}.
__global__ __launch_bounds__(256) void fill_kernel(
    const int* __restrict__ dst, const int* __restrict__ src,
    int* __restrict__ cursor, int2* __restrict__ edat)
{
    const int e = blockIdx.x * 256 + threadIdx.x;
    if (e < N_EDGES) {
        const int p = atomicAdd(&cursor[dst[e]], 1);
        edat[p] = make_int2(e, src[e]);
    }
}

// ---------------------------------------------------------------------------
// Aggregation body: float4 per lane, 32 lanes per 512B row, 2 nodes/wave.
// Indices from edat[].y via alignment-peeled int4 pair-loads.
// ---------------------------------------------------------------------------
__device__ __forceinline__ void agg_body2(
    int v, int l32,
    const float* __restrict__ hv, const int2* __restrict__ edat,
    const int* __restrict__ rowptr,
    ushort_t* __restrict__ S_hi, ushort_t* __restrict__ S_lo)
{
    if (v >= N_NODES) return;
    const int r0 = rowptr[v], r1 = rowptr[v + 1];
    const float4* hv4 = (const float4*)hv;
    float4 acc = make_float4(0.f, 0.f, 0.f, 0.f);
    int i = r0;
    if (i < r1 && (i & 1)) {               // peel to 16B-aligned pair boundary
        acc = f4add(acc, hv4[(size_t)edat[i].y * 32 + l32]);
        ++i;
    }
    for (; i + 8 <= r1; i += 8) {
        const int4 p01 = *(const int4*)&edat[i];       // e0,s0,e1,s1
        const int4 p23 = *(const int4*)&edat[i + 2];
        const int4 p45 = *(const int4*)&edat[i + 4];
        const int4 p67 = *(const int4*)&edat[i + 6];
        const float4 a0 = hv4[(size_t)p01.y * 32 + l32];
        const float4 a1 = hv4[(size_t)p01.w * 32 + l32];
        const float4 a2 = hv4[(size_t)p23.y * 32 + l32];
        const float4 a3 = hv4[(size_t)p23.w * 32 + l32];
        const float4 a4 = hv4[(size_t)p45.y * 32 + l32];
        const float4 a5 = hv4[(size_t)p45.w * 32 + l32];
        const float4 a6 = hv4[(size_t)p67.y * 32 + l32];
        const float4 a7 = hv4[(size_t)p67.w * 32 + l32];
        acc = f4add(acc, f4add(f4add(f4add(a0, a1), f4add(a2, a3)),
                               f4add(f4add(a4, a5), f4add(a6, a7))));
    }
    for (; i < r1; ++i)
        acc = f4add(acc, hv4[(size_t)edat[i].y * 32 + l32]);
    uint2 hh, ll;
    split2(acc.x, acc.y, hh.x, ll.x);
    split2(acc.z, acc.w, hh.y, ll.y);
    ((uint2*)S_hi)[(size_t)v * 32 + l32] = hh;
    ((uint2*)S_lo)[(size_t)v * 32 + l32] = ll;
}

__global__ __launch_bounds__(256) void agg_kernel(
    const float* __restrict__ hv, const int2* __restrict__ edat,
    const int* __restrict__ rowptr,
    ushort_t* __restrict__ S_hi, ushort_t* __restrict__ S_lo)
{
    agg_body2(blockIdx.x * 8 + (threadIdx.x >> 5), threadIdx.x & 31,
              hv, edat, rowptr, S_hi, S_lo);
}

// ---------------------------------------------------------------------------
// aux_kernel: agg(t=0) + esum + convert_w + convert_gatew merged (all
// fill-gated). agg blocks first (longest pole). esum reads edat[].x.
// ---------------------------------------------------------------------------
__global__ __launch_bounds__(256) void aux_kernel(
    // agg(t=0)
    const float* __restrict__ hv, const int2* __restrict__ edat,
    const int* __restrict__ rowptr,
    ushort_t* __restrict__ S_hi, ushort_t* __restrict__ S_lo,
    // esum
    const float* __restrict__ he, float* __restrict__ E,
    // convert_w
    const float* __restrict__ Wmsg,
    ushort_t* __restrict__ Wt_hi, ushort_t* __restrict__ Wt_lo,
    // convert_gatew
    const float* __restrict__ W_ih, const float* __restrict__ W_hh,
    ushort_t* __restrict__ Bih_hi, ushort_t* __restrict__ Bih_lo,
    ushort_t* __restrict__ Bhh_hi, ushort_t* __restrict__ Bhh_lo)
{
    const int b = blockIdx.x;
    if (b < AGG_B) {
        agg_body2(b * 8 + (threadIdx.x >> 5), threadIdx.x & 31,
                  hv, edat, rowptr, S_hi, S_lo);
    } else if (b < AGG_B + ESUM_B) {
        const int v = (b - AGG_B) * 32 + (threadIdx.x >> 3);
        const int c4 = threadIdx.x & 7;
        if (v < N_NODES) {
            const int r0 = rowptr[v], r1 = rowptr[v + 1];
            const float4* he4 = (const float4*)he;
            float4 acc = make_float4(0.f, 0.f, 0.f, 0.f);
            int i = r0;
            if (i < r1 && (i & 1)) {
                acc = f4add(acc, he4[(size_t)edat[i].x * 8 + c4]);
                ++i;
            }
            for (; i + 4 <= r1; i += 4) {
                const int4 p01 = *(const int4*)&edat[i];
                const int4 p23 = *(const int4*)&edat[i + 2];
                const float4 a0 = he4[(size_t)p01.x * 8 + c4];
                const float4 a1 = he4[(size_t)p01.z * 8 + c4];
                const float4 a2 = he4[(size_t)p23.x * 8 + c4];
                const float4 a3 = he4[(size_t)p23.z * 8 + c4];
                acc = f4add(acc, f4add(f4add(a0, a1), f4add(a2, a3)));
            }
            for (; i < r1; ++i)
                acc = f4add(acc, he4[(size_t)edat[i].x * 8 + c4]);
            ((float4*)E)[(size_t)v * 8 + c4] = acc;
        }
    } else if (b < AGG_B + ESUM_B + CW_B) {
        const int id = (b - AGG_B - ESUM_B) * 256 + threadIdx.x;  // < 73728 exactly
        const int tt = id / (CAT * AD);
        const int q  = id % (CAT * AD);
        const int j  = q & 7;
        const int lr = (q >> 3) & 15;
        const int kq = (q >> 7) & 3;
        const int ks = (q >> 9) % 9;
        const int gnt = q / 4608;
        const int n  = gnt * 16 + lr;
        const int kn = ks * 32 + kq * 8 + j;
        const int ko = kn < 128 ? kn : (kn < 160 ? kn + 128 : kn - 32);
        const float w = Wmsg[(size_t)tt * CAT * AD + (size_t)ko * AD + n];
        const unsigned int hi = f2bf(w);
        const float r = w - __uint_as_float(hi << 16);
        const size_t o = (size_t)tt * (CAT * AD) + q;
        Wt_hi[o] = (ushort_t)hi;
        Wt_lo[o] = (ushort_t)f2bf(r);
    } else {
        const int id = (b - AGG_B - ESUM_B - CW_B) * 256 + threadIdx.x;  // < 196608
        const int t   = id / 98304;
        const int rem = id % 98304;
        const int mat = rem / 49152;
        const int q   = rem % 49152;
        const int nt = q / 2048,  r1 = q % 2048;
        const int ks = r1 / 512,  r2 = r1 % 512;
        const int kq = r2 / 128,  r3 = r2 % 128;
        const int lr = r3 / 8,    j  = r3 % 8;
        const int wv = nt / 6, within = nt % 6;
        const int gate = within % 3, hf = within / 3;
        const int n = gate * 128 + wv * 32 + hf * 16 + lr;   // permuted column
        const int k = ks * 32 + kq * 8 + j;
        const float* W = mat ? W_hh : W_ih;
        const float w = W[(size_t)t * ND * G3 + (size_t)k * G3 + n];
        const unsigned int hi = f2bf(w);
        const float res = w - __uint_as_float(hi << 16);
        const size_t o = (size_t)t * 49152 + q;
        if (mat) { Bhh_hi[o] = (ushort_t)hi; Bhh_lo[o] = (ushort_t)f2bf(res); }
        else     { Bih_hi[o] = (ushort_t)hi; Bih_lo[o] = (ushort_t)f2bf(res); }
    }
}

// ---------------------------------------------------------------------------
// Fused msg+GRU, M=32 per block. EXACT Round-6 kernel (proven 69.5 us,
// 68 VGPR, no spill): Round-3 structure + s_setprio(1) around MFMA clusters.
// Lesson ledger: (256,4) -> 64-VGPR cap -> spill (R5, 138us);
//                (256,2)+M=64 -> needs ~200 VGPR -> spill (R4, 118us);
//                (256,3) -> 68-76 VGPR natural fit (R3/R6). Do not touch.
// ---------------------------------------------------------------------------
__global__ __launch_bounds__(256, 3) void fused_msg_gru_kernel(
    const ushort_t* __restrict__ S_hi, const ushort_t* __restrict__ S_lo,
    const float* __restrict__ h_cur, const float* __restrict__ E,
    const int* __restrict__ rowptr,
    const ushort_t* __restrict__ Wt_hi, const ushort_t* __restrict__ Wt_lo,
    const float* __restrict__ bmsg,
    const ushort_t* __restrict__ Bih_hi, const ushort_t* __restrict__ Bih_lo,
    const ushort_t* __restrict__ Bhh_hi, const ushort_t* __restrict__ Bhh_lo,
    const float* __restrict__ b_ih, const float* __restrict__ b_hh,
    float* __restrict__ h_out)
{
    __shared__ __align__(16) char smem[37888];
    ushort_t* xh    = (ushort_t*)smem;           // [32][168] = 10752 B
    ushort_t* xl    = xh + 32 * XP2;             // [32][168] = 10752 B
    ushort_t* sh_hi = xl + 32 * XP2;             // [32][128] swz = 8192 B
    ushort_t* sh_lo = sh_hi + 32 * 128;          // [32][128] swz = 8192 B
    // phase C/D: sa aliases xh/xl region (16384 <= 21504)
    ushort_t* sa_hi = (ushort_t*)smem;           // [32][128] swz
    ushort_t* sa_lo = sa_hi + 32 * 128;
    __shared__ float sdeg[32];

    const int t    = threadIdx.x;
    const int wave = t >> 6;
    const int lane = t & 63;
    const int kq   = lane >> 4;
    const int lr   = lane & 15;
    const int n0   = blockIdx.x * 32;

    const float mbias0 = bmsg[wave * 32 + lr];
    const float mbias1 = bmsg[wave * 32 + 16 + lr];

    // ---- phase A: stage X=[S|E] and h ----
    {
        const int row = t >> 3, c8 = t & 7;
        const int n = min(n0 + row, N_NODES - 1);
        if (t < 32) {
            const int nn = min(n0 + t, N_NODES - 1);
            sdeg[t] = (float)(rowptr[nn + 1] - rowptr[nn]);
        }
        // S: pre-split copies -> X cols 0..127
        {
            const uint4* ph = (const uint4*)(S_hi + (size_t)n * ND + c8 * 16);
            const uint4* pl = (const uint4*)(S_lo + (size_t)n * ND + c8 * 16);
            *(uint4*)&xh[row * XP2 + c8 * 16]     = ph[0];
            *(uint4*)&xh[row * XP2 + c8 * 16 + 8] = ph[1];
            *(uint4*)&xl[row * XP2 + c8 * 16]     = pl[0];
            *(uint4*)&xl[row * XP2 + c8 * 16 + 8] = pl[1];
        }
        // h: split into swizzled sh (serves both Wd-msg term and GRU)
        {
            const float4* hp = (const float4*)(h_cur + (size_t)n * ND + c8 * 16);
            const float4 v0 = hp[0], v1 = hp[1], v2 = hp[2], v3 = hp[3];
            uint4 h0, h1, l0, l1;
            split2(v0.x, v0.y, h0.x, l0.x); split2(v0.z, v0.w, h0.y, l0.y);
            split2(v1.x, v1.y, h0.z, l0.z); split2(v1.z, v1.w, h0.w, l0.w);
            split2(v2.x, v2.y, h1.x, l1.x); split2(v2.z, v2.w, h1.y, l1.y);
            split2(v3.x, v3.y, h1.z, l1.z); split2(v3.z, v3.w, h1.w, l1.w);
            const int so  = (row * 128 + c8 * 16)     ^ ((row & 7) << 3);
            const int so2 = (row * 128 + c8 * 16 + 8) ^ ((row & 7) << 3);
            *(uint4*)(sh_hi + so)  = h0;  *(uint4*)(sh_hi + so2) = h1;
            *(uint4*)(sh_lo + so)  = l0;  *(uint4*)(sh_lo + so2) = l1;
        }
        // E -> X cols 128..159
        {
            const float4 e4 = *(const float4*)(E + (size_t)n * ED + c8 * 4);
            uint2 h0, l0;
            split2(e4.x, e4.y, h0.x, l0.x); split2(e4.z, e4.w, h0.y, l0.y);
            *(uint2*)&xh[row * XP2 + 128 + c8 * 4] = h0;
            *(uint2*)&xl[row * XP2 + 128 + c8 * 4] = l0;
        }
    }
    __syncthreads();

    // ---- phase B: aX = X@W[Ws|We] (ks 0..4), aP = h@Wd (ks 5..8) ----
    f32x4 aX00 = {0.f,0.f,0.f,0.f}, aX01 = {0.f,0.f,0.f,0.f};
    f32x4 aX10 = {0.f,0.f,0.f,0.f}, aX11 = {0.f,0.f,0.f,0.f};
    f32x4 aP00 = {0.f,0.f,0.f,0.f}, aP01 = {0.f,0.f,0.f,0.f};
    f32x4 aP10 = {0.f,0.f,0.f,0.f}, aP11 = {0.f,0.f,0.f,0.f};
    {
        const size_t wb0 = (size_t)(wave * 2 + 0) * 4608 + kq * 128 + lr * 8;
        const size_t wb1 = (size_t)(wave * 2 + 1) * 4608 + kq * 128 + lr * 8;
        const ushort_t* wh0 = Wt_hi + wb0;  const ushort_t* wl0 = Wt_lo + wb0;
        const ushort_t* wh1 = Wt_hi + wb1;  const ushort_t* wl1 = Wt_lo + wb1;
        #pragma unroll
        for (int ks = 0; ks < 5; ++ks) {
            const int ko = ks * 32 + kq * 8;
            const bfrag a0h = *(const bfrag*)&xh[lr * XP2 + ko];
            const bfrag a0l = *(const bfrag*)&xl[lr * XP2 + ko];
            const bfrag a1h = *(const bfrag*)&xh[(16 + lr) * XP2 + ko];
            const bfrag a1l = *(const bfrag*)&xl[(16 + lr) * XP2 + ko];
            const bfrag b0h = *(const bfrag*)(wh0 + ks * 512);
            const bfrag b0l = *(const bfrag*)(wl0 + ks * 512);
            const bfrag b1h = *(const bfrag*)(wh1 + ks * 512);
            const bfrag b1l = *(const bfrag*)(wl1 + ks * 512);
            __builtin_amdgcn_s_setprio(1);
            aX00 = __builtin_amdgcn_mfma_f32_16x16x32_bf16(a0h, b0h, aX00, 0, 0, 0);
            aX00 = __builtin_amdgcn_mfma_f32_16x16x32_bf16(a0l, b0h, aX00, 0, 0, 0);
            aX00 = __builtin_amdgcn_mfma_f32_16x16x32_bf16(a0h, b0l, aX00, 0, 0, 0);
            aX01 = __builtin_amdgcn_mfma_f32_16x16x32_bf16(a0h, b1h, aX01, 0, 0, 0);
            aX01 = __builtin_amdgcn_mfma_f32_16x16x32_bf16(a0l, b1h, aX01, 0, 0, 0);
            aX01 = __builtin_amdgcn_mfma_f32_16x16x32_bf16(a0h, b1l, aX01, 0, 0, 0);
            aX10 = __builtin_amdgcn_mfma_f32_16x16x32_bf16(a1h, b0h, aX10, 0, 0, 0);
            aX10 = __builtin_amdgcn_mfma_f32_16x16x32_bf16(a1l, b0h, aX10, 0, 0, 0);
            aX10 = __builtin_amdgcn_mfma_f32_16x16x32_bf16(a1h, b0l, aX10, 0, 0, 0);
            aX11 = __builtin_amdgcn_mfma_f32_16x16x32_bf16(a1h, b1h, aX11, 0, 0, 0);
            aX11 = __builtin_amdgcn_mfma_f32_16x16x32_bf16(a1l, b1h, aX11, 0, 0, 0);
            aX11 = __builtin_amdgcn_mfma_f32_16x16x32_bf16(a1h, b1l, aX11, 0, 0, 0);
            __builtin_amdgcn_s_setprio(0);
        }
        #pragma unroll
        for (int ks = 5; ks < 9; ++ks) {
            const int hk = (ks - 5) * 32 + kq * 8;
            const int o0 = (lr * 128 + hk)        ^ ((lr & 7) << 3);
            const int o1 = ((16 + lr) * 128 + hk) ^ ((lr & 7) << 3);
            const bfrag a0h = *(const bfrag*)(sh_hi + o0);
            const bfrag a0l = *(const bfrag*)(sh_lo + o0);
            const bfrag a1h = *(const bfrag*)(sh_hi + o1);
            const bfrag a1l = *(const bfrag*)(sh_lo + o1);
            const bfrag b0h = *(const bfrag*)(wh0 + ks * 512);
            const bfrag b0l = *(const bfrag*)(wl0 + ks * 512);
            const bfrag b1h = *(const bfrag*)(wh1 + ks * 512);
            const bfrag b1l = *(const bfrag*)(wl1 + ks * 512);
            __builtin_amdgcn_s_setprio(1);
            aP00 = __builtin_amdgcn_mfma_f32_16x16x32_bf16(a0h, b0h, aP00, 0, 0, 0);
            aP00 = __builtin_amdgcn_mfma_f32_16x16x32_bf16(a0l, b0h, aP00, 0, 0, 0);
            aP00 = __builtin_amdgcn_mfma_f32_16x16x32_bf16(a0h, b0l, aP00, 0, 0, 0);
            aP01 = __builtin_amdgcn_mfma_f32_16x16x32_bf16(a0h, b1h, aP01, 0, 0, 0);
            aP01 = __builtin_amdgcn_mfma_f32_16x16x32_bf16(a0l, b1h, aP01, 0, 0, 0);
            aP01 = __builtin_amdgcn_mfma_f32_16x16x32_bf16(a0h, b1l, aP01, 0, 0, 0);
            aP10 = __builtin_amdgcn_mfma_f32_16x16x32_bf16(a1h, b0h, aP10, 0, 0, 0);
            aP10 = __builtin_amdgcn_mfma_f32_16x16x32_bf16(a1l, b0h, aP10, 0, 0, 0);
            aP10 = __builtin_amdgcn_mfma_f32_16x16x32_bf16(a1h, b0l, aP10, 0, 0, 0);
            aP11 = __builtin_amdgcn_mfma_f32_16x16x32_bf16(a1h, b1h, aP11, 0, 0, 0);
            aP11 = __builtin_amdgcn_mfma_f32_16x16x32_bf16(a1l, b1h, aP11, 0, 0, 0);
            aP11 = __builtin_amdgcn_mfma_f32_16x16x32_bf16(a1h, b1l, aP11, 0, 0, 0);
            __builtin_amdgcn_s_setprio(0);
        }
    }
    __syncthreads();   // xh/xl reads complete before aliasing writes

    // ---- phase C: a = aX + deg*(aP + bias) -> split -> swizzled sa ----
    #pragma unroll
    for (int r = 0; r < 4; ++r) {
        const int row0 = kq * 4 + r;
        const int row1 = 16 + row0;
        const int c0 = wave * 32 + lr, c1 = c0 + 16;
        const float d0 = sdeg[row0], d1 = sdeg[row1];
        ushort_t h, l;
        split1(aX00[r] + d0 * (aP00[r] + mbias0), h, l);
        { const int o = (row0 * 128 + c0) ^ ((row0 & 7) << 3); sa_hi[o] = h; sa_lo[o] = l; }
        split1(aX01[r] + d0 * (aP01[r] + mbias1), h, l);
        { const int o = (row0 * 128 + c1) ^ ((row0 & 7) << 3); sa_hi[o] = h; sa_lo[o] = l; }
        split1(aX10[r] + d1 * (aP10[r] + mbias0), h, l);
        { const int o = (row1 * 128 + c0) ^ ((row1 & 7) << 3); sa_hi[o] = h; sa_lo[o] = l; }
        split1(aX11[r] + d1 * (aP11[r] + mbias1), h, l);
        { const int o = (row1 * 128 + c1) ^ ((row1 & 7) << 3); sa_hi[o] = h; sa_lo[o] = l; }
    }
    __syncthreads();

    // ---- phase D+E: two half-passes, gates in-register via permuted cols ----
    #pragma unroll
    for (int half = 0; half < 2; ++half) {
        f32x4 ai[2][3], ah2[2][3];
        #pragma unroll
        for (int m = 0; m < 2; ++m)
            #pragma unroll
            for (int g = 0; g < 3; ++g) {
                ai[m][g]  = (f32x4){0.f, 0.f, 0.f, 0.f};
                ah2[m][g] = (f32x4){0.f, 0.f, 0.f, 0.f};
            }
        #pragma unroll
        for (int ks = 0; ks < 4; ++ks) {
            bfrag afh[2], afl[2], hfh[2], hfl[2];
            #pragma unroll
            for (int m = 0; m < 2; ++m) {
                const int o = ((m * 16 + lr) * 128 + ks * 32 + kq * 8) ^ ((lr & 7) << 3);
                afh[m] = *(const bfrag*)(sa_hi + o);
                afl[m] = *(const bfrag*)(sa_lo + o);
                hfh[m] = *(const bfrag*)(sh_hi + o);
                hfl[m] = *(const bfrag*)(sh_lo + o);
            }
            #pragma unroll
            for (int g = 0; g < 3; ++g) {
                const int gnt = wave * 6 + half * 3 + g;
                const size_t bo = (size_t)(gnt * 2048 + ks * 512 + kq * 128 + lr * 8);
                const bfrag bih_h = *(const bfrag*)(Bih_hi + bo);
                const bfrag bih_l = *(const bfrag*)(Bih_lo + bo);
                const bfrag bhh_h = *(const bfrag*)(Bhh_hi + bo);
                const bfrag bhh_l = *(const bfrag*)(Bhh_lo + bo);
                __builtin_amdgcn_s_setprio(1);
                #pragma unroll
                for (int m = 0; m < 2; ++m) {
                    ai[m][g]  = __builtin_amdgcn_mfma_f32_16x16x32_bf16(afh[m], bih_h, ai[m][g], 0, 0, 0);
                    ai[m][g]  = __builtin_amdgcn_mfma_f32_16x16x32_bf16(afl[m], bih_h, ai[m][g], 0, 0, 0);
                    ai[m][g]  = __builtin_amdgcn_mfma_f32_16x16x32_bf16(afh[m], bih_l, ai[m][g], 0, 0, 0);
                    ah2[m][g] = __builtin_amdgcn_mfma_f32_16x16x32_bf16(hfh[m], bhh_h, ah2[m][g], 0, 0, 0);
                    ah2[m][g] = __builtin_amdgcn_mfma_f32_16x16x32_bf16(hfl[m], bhh_h, ah2[m][g], 0, 0, 0);
                    ah2[m][g] = __builtin_amdgcn_mfma_f32_16x16x32_bf16(hfh[m], bhh_l, ah2[m][g], 0, 0, 0);
                }
                __builtin_amdgcn_s_setprio(0);
            }
        }
        // epilogue for this half: pure registers, exact fp32 h from L2
        const int c = wave * 32 + half * 16 + lr;
        const float br  = b_ih[c] + b_hh[c];
        const float bz  = b_ih[128 + c] + b_hh[128 + c];
        const float bin = b_ih[256 + c];
        const float bhn = b_hh[256 + c];
        #pragma unroll
        for (int m = 0; m < 2; ++m)
            #pragma unroll
            for (int r = 0; r < 4; ++r) {
                const int nn = n0 + m * 16 + kq * 4 + r;
                if (nn < N_NODES) {
                    const float hc = h_cur[(size_t)nn * ND + c];
                    const float rg = 1.f / (1.f + __expf(-(ai[m][0][r] + ah2[m][0][r] + br)));
                    const float zg = 1.f / (1.f + __expf(-(ai[m][1][r] + ah2[m][1][r] + bz)));
                    const float npre = ai[m][2][r] + bin + rg * (ah2[m][2][r] + bhn);
                    const float ng = 1.f - 2.f / (__expf(2.f * npre) + 1.f);   // tanh, overflow-safe
                    h_out[(size_t)nn * ND + c] = (1.f - zg) * ng + zg * hc;
                }
            }
    }
}

// ---------------------------------------------------------------------------
extern "C" void kernel_launch(void* const* d_in, const int* in_sizes, int n_in,
                              void* d_out, int out_size, void* d_ws, size_t ws_size,
                              hipStream_t stream)
{
    const float* hv   = (const float*)d_in[0];
    const float* he   = (const float*)d_in[1];
    const int*   src  = (const int*)d_in[2];
    const int*   dst  = (const int*)d_in[3];
    const float* Wmsg = (const float*)d_in[4];
    const float* bmsg = (const float*)d_in[5];
    const float* Wih  = (const float*)d_in[6];
    const float* Whh  = (const float*)d_in[7];
    const float* bih  = (const float*)d_in[8];
    const float* bhh  = (const float*)d_in[9];
    float* out = (float*)d_out;

    const int nscan = ((N_NODES + SCAN_BS - 1) / SCAN_BS) * SCAN_BS;  // 50176
    const int nblk  = nscan / SCAN_BS;                                // 98

    char* p = (char*)d_ws;
    ushort_t* S_hi = (ushort_t*)p;            p += (size_t)N_NODES * ND * 2;
    ushort_t* S_lo = (ushort_t*)p;            p += (size_t)N_NODES * ND * 2;
    float* E = (float*)p;                     p += (size_t)N_NODES * ED * 4;   // 6.4 MB
    ushort_t* Wt_hi = (ushort_t*)p;           p += (size_t)2 * AD * CAT * 2;
    ushort_t* Wt_lo = (ushort_t*)p;           p += (size_t)2 * AD * CAT * 2;
    ushort_t* Bih_hi = (ushort_t*)p;          p += (size_t)2 * G3 * ND * 2;
    ushort_t* Bih_lo = (ushort_t*)p;          p += (size_t)2 * G3 * ND * 2;
    ushort_t* Bhh_hi = (ushort_t*)p;          p += (size_t)2 * G3 * ND * 2;
    ushort_t* Bhh_lo = (ushort_t*)p;          p += (size_t)2 * G3 * ND * 2;
    int* deg    = (int*)p;                    p += (size_t)nscan * 4;
    int* rowptr = (int*)p;                    p += (size_t)nscan * 4;
    int* cursor = (int*)p;                    p += (size_t)nscan * 4;
    int* bsum   = (int*)p;                    p += 128 * 4;
    int2* edat  = (int2*)p;                   p += (size_t)N_EDGES * 8;

    // ---- CSR sort chain ----
    hipMemsetAsync(deg, 0, (size_t)nscan * 4, stream);
    hist_kernel<<<(N_EDGES + 255) / 256, 256, 0, stream>>>(dst, deg);
    scan_block_kernel<<<nblk, SCAN_BS, 0, stream>>>(deg, rowptr, bsum, nscan);
    scan_sums_kernel<<<1, 128, 0, stream>>>(bsum, nblk);
    scan_add_kernel<<<nblk, SCAN_BS, 0, stream>>>(rowptr, cursor, bsum, nscan);
    fill_kernel<<<(N_EDGES + 255) / 256, 256, 0, stream>>>(dst, src, cursor, edat);

    // ---- merged: agg(t=0) + esum + weight converts (all fill-gated) ----
    aux_kernel<<<AGG_B + ESUM_B + CW_B + CG_B, 256, 0, stream>>>(
        hv, edat, rowptr, S_hi, S_lo,
        he, E,
        Wmsg, Wt_hi, Wt_lo,
        Wih, Whh, Bih_hi, Bih_lo, Bhh_hi, Bhh_lo);

    const int tile_blocks = (N_NODES + 31) / 32;   // 1563

    for (int t = 0; t < 2; ++t) {
        const float* h_cur = (t == 0) ? hv : out;
        if (t == 1)
            agg_kernel<<<(N_NODES + 7) / 8, 256, 0, stream>>>(
                h_cur, edat, rowptr, S_hi, S_lo);
        fused_msg_gru_kernel<<<tile_blocks, 256, 0, stream>>>(
            S_hi, S_lo, h_cur, E, rowptr,
            Wt_hi + (size_t)t * AD * CAT, Wt_lo + (size_t)t * AD * CAT,
            bmsg + (size_t)t * AD,
            Bih_hi + (size_t)t * G3 * ND, Bih_lo + (size_t)t * G3 * ND,
            Bhh_hi + (size_t)t * G3 * ND, Bhh_lo + (size_t)t * G3 * ND,
            bih + (size_t)t * G3, bhh + (size_t)t * G3, out);
    }
}

// Round 10
// 489.899 us; speedup vs baseline: 1.0389x; 1.0389x over previous
//
#include <hip/hip_runtime.h>

#define N_NODES 50000
#define N_EDGES 800000
#define ND 128
#define ED 32
#define AD 128
#define CAT 288   // 2*ND + ED
#define G3 384    // 3*ND

#define XP2 168       // LDS row stride for X=[S(128)|E(32)] (bf16 elems), 16B-aligned
#define SCAN_BS 512

// aux_kernel block partition: agg first (longest), then esum, then converts
#define AGG_B 6250    // 50000 nodes / 8 per block (2 nodes per wave, float4 lanes)
#define ESUM_B 1563   // 50000 nodes / 32 per block (8 lanes x float4 per node)
#define CW_B 288      // 73728 / 256
#define CG_B 768      // 196608 / 256

typedef unsigned short ushort_t;
typedef __attribute__((ext_vector_type(8))) short bfrag;   // 8 bf16 (4 VGPRs)
typedef __attribute__((ext_vector_type(4))) float f32x4;   // MFMA accumulator

__device__ __forceinline__ unsigned int f2bf(float f) {
    unsigned int u = __float_as_uint(f);
    return (u + 0x7FFFu + ((u >> 16) & 1u)) >> 16;   // RTNE to bf16
}
__device__ __forceinline__ void split2(float a, float b,
                                       unsigned int& hi, unsigned int& lo) {
    const unsigned int ha = f2bf(a), hb = f2bf(b);
    const float ra = a - __uint_as_float(ha << 16);
    const float rb = b - __uint_as_float(hb << 16);
    hi = ha | (hb << 16);
    lo = f2bf(ra) | (f2bf(rb) << 16);
}
__device__ __forceinline__ void split1(float a, ushort_t& hi, ushort_t& lo) {
    const unsigned int ha = f2bf(a);
    const float ra = a - __uint_as_float(ha << 16);
    hi = (ushort_t)ha;
    lo = (ushort_t)f2bf(ra);
}
__device__ __forceinline__ float4 f4add(const float4 a, const float4 b) {
    return make_float4(a.x + b.x, a.y + b.y, a.z + b.z, a.w + b.w);
}

// ========================= counting sort by dst ============================
// hist also captures each edge's rank within its dst bucket (the atomic's
// return value, previously discarded). fill then needs NO atomics.
__global__ __launch_bounds__(256) void hist_kernel(
    const int* __restrict__ dst, int* __restrict__ deg,
    int* __restrict__ rank_)
{
    const int e = blockIdx.x * 256 + threadIdx.x;
    if (e < N_EDGES) rank_[e] = atomicAdd(&deg[dst[e]], 1);
}

__global__ __launch_bounds__(SCAN_BS) void scan_block_kernel(
    const int* __restrict__ in, int* __restrict__ out,
    int* __restrict__ bsum, int n)
{
    __shared__ int s[SCAN_BS];
    const int g = blockIdx.x * SCAN_BS + threadIdx.x;
    const int v = (g < n) ? in[g] : 0;
    s[threadIdx.x] = v;
    __syncthreads();
    for (int off = 1; off < SCAN_BS; off <<= 1) {
        const int x = (threadIdx.x >= off) ? s[threadIdx.x - off] : 0;
        __syncthreads();
        s[threadIdx.x] += x;
        __syncthreads();
    }
    if (g < n) out[g] = s[threadIdx.x] - v;   // exclusive
    if (threadIdx.x == SCAN_BS - 1) bsum[blockIdx.x] = s[threadIdx.x];
}

__global__ __launch_bounds__(128) void scan_sums_kernel(int* __restrict__ bsum, int nb)
{
    __shared__ int s[128];
    const int i = threadIdx.x;
    s[i] = (i < nb) ? bsum[i] : 0;
    __syncthreads();
    if (i == 0) {
        int acc = 0;
        for (int k = 0; k < nb; ++k) { const int t = s[k]; s[k] = acc; acc += t; }
    }
    __syncthreads();
    if (i < nb) bsum[i] = s[i];
}

__global__ __launch_bounds__(SCAN_BS) void scan_add_kernel(
    int* __restrict__ rowptr, const int* __restrict__ bsum, int n)
{
    const int g = blockIdx.x * SCAN_BS + threadIdx.x;
    if (g < n) rowptr[g] += bsum[blockIdx.x];
}

// fill: NO atomics (position = rowptr[dst] + rank). One 8B store per edge.
__global__ __launch_bounds__(256) void fill_kernel(
    const int* __restrict__ dst, const int* __restrict__ src,
    const int* __restrict__ rowptr, const int* __restrict__ rank_,
    int2* __restrict__ edat)
{
    const int e = blockIdx.x * 256 + threadIdx.x;
    if (e < N_EDGES) {
        const int p = rowptr[dst[e]] + rank_[e];
        edat[p] = make_int2(e, src[e]);
    }
}

// ---------------------------------------------------------------------------
// Aggregation body: float4 per lane, 32 lanes per 512B row, 2 nodes/wave.
// Indices from edat[].y via alignment-peeled int4 pair-loads.
// ---------------------------------------------------------------------------
__device__ __forceinline__ void agg_body2(
    int v, int l32,
    const float* __restrict__ hv, const int2* __restrict__ edat,
    const int* __restrict__ rowptr,
    ushort_t* __restrict__ S_hi, ushort_t* __restrict__ S_lo)
{
    if (v >= N_NODES) return;
    const int r0 = rowptr[v], r1 = rowptr[v + 1];
    const float4* hv4 = (const float4*)hv;
    float4 acc = make_float4(0.f, 0.f, 0.f, 0.f);
    int i = r0;
    if (i < r1 && (i & 1)) {               // peel to 16B-aligned pair boundary
        acc = f4add(acc, hv4[(size_t)edat[i].y * 32 + l32]);
        ++i;
    }
    for (; i + 8 <= r1; i += 8) {
        const int4 p01 = *(const int4*)&edat[i];       // e0,s0,e1,s1
        const int4 p23 = *(const int4*)&edat[i + 2];
        const int4 p45 = *(const int4*)&edat[i + 4];
        const int4 p67 = *(const int4*)&edat[i + 6];
        const float4 a0 = hv4[(size_t)p01.y * 32 + l32];
        const float4 a1 = hv4[(size_t)p01.w * 32 + l32];
        const float4 a2 = hv4[(size_t)p23.y * 32 + l32];
        const float4 a3 = hv4[(size_t)p23.w * 32 + l32];
        const float4 a4 = hv4[(size_t)p45.y * 32 + l32];
        const float4 a5 = hv4[(size_t)p45.w * 32 + l32];
        const float4 a6 = hv4[(size_t)p67.y * 32 + l32];
        const float4 a7 = hv4[(size_t)p67.w * 32 + l32];
        acc = f4add(acc, f4add(f4add(f4add(a0, a1), f4add(a2, a3)),
                               f4add(f4add(a4, a5), f4add(a6, a7))));
    }
    for (; i < r1; ++i)
        acc = f4add(acc, hv4[(size_t)edat[i].y * 32 + l32]);
    uint2 hh, ll;
    split2(acc.x, acc.y, hh.x, ll.x);
    split2(acc.z, acc.w, hh.y, ll.y);
    ((uint2*)S_hi)[(size_t)v * 32 + l32] = hh;
    ((uint2*)S_lo)[(size_t)v * 32 + l32] = ll;
}

__global__ __launch_bounds__(256) void agg_kernel(
    const float* __restrict__ hv, const int2* __restrict__ edat,
    const int* __restrict__ rowptr,
    ushort_t* __restrict__ S_hi, ushort_t* __restrict__ S_lo)
{
    agg_body2(blockIdx.x * 8 + (threadIdx.x >> 5), threadIdx.x & 31,
              hv, edat, rowptr, S_hi, S_lo);
}

// ---------------------------------------------------------------------------
// aux_kernel: agg(t=0) + esum + convert_w + convert_gatew merged (all
// fill-gated). agg blocks first (longest pole). esum reads edat[].x.
// ---------------------------------------------------------------------------
__global__ __launch_bounds__(256) void aux_kernel(
    // agg(t=0)
    const float* __restrict__ hv, const int2* __restrict__ edat,
    const int* __restrict__ rowptr,
    ushort_t* __restrict__ S_hi, ushort_t* __restrict__ S_lo,
    // esum
    const float* __restrict__ he, float* __restrict__ E,
    // convert_w
    const float* __restrict__ Wmsg,
    ushort_t* __restrict__ Wt_hi, ushort_t* __restrict__ Wt_lo,
    // convert_gatew
    const float* __restrict__ W_ih, const float* __restrict__ W_hh,
    ushort_t* __restrict__ Bih_hi, ushort_t* __restrict__ Bih_lo,
    ushort_t* __restrict__ Bhh_hi, ushort_t* __restrict__ Bhh_lo)
{
    const int b = blockIdx.x;
    if (b < AGG_B) {
        agg_body2(b * 8 + (threadIdx.x >> 5), threadIdx.x & 31,
                  hv, edat, rowptr, S_hi, S_lo);
    } else if (b < AGG_B + ESUM_B) {
        const int v = (b - AGG_B) * 32 + (threadIdx.x >> 3);
        const int c4 = threadIdx.x & 7;
        if (v < N_NODES) {
            const int r0 = rowptr[v], r1 = rowptr[v + 1];
            const float4* he4 = (const float4*)he;
            float4 acc = make_float4(0.f, 0.f, 0.f, 0.f);
            int i = r0;
            if (i < r1 && (i & 1)) {
                acc = f4add(acc, he4[(size_t)edat[i].x * 8 + c4]);
                ++i;
            }
            for (; i + 4 <= r1; i += 4) {
                const int4 p01 = *(const int4*)&edat[i];
                const int4 p23 = *(const int4*)&edat[i + 2];
                const float4 a0 = he4[(size_t)p01.x * 8 + c4];
                const float4 a1 = he4[(size_t)p01.z * 8 + c4];
                const float4 a2 = he4[(size_t)p23.x * 8 + c4];
                const float4 a3 = he4[(size_t)p23.z * 8 + c4];
                acc = f4add(acc, f4add(f4add(a0, a1), f4add(a2, a3)));
            }
            for (; i < r1; ++i)
                acc = f4add(acc, he4[(size_t)edat[i].x * 8 + c4]);
            ((float4*)E)[(size_t)v * 8 + c4] = acc;
        }
    } else if (b < AGG_B + ESUM_B + CW_B) {
        const int id = (b - AGG_B - ESUM_B) * 256 + threadIdx.x;  // < 73728 exactly
        const int tt = id / (CAT * AD);
        const int q  = id % (CAT * AD);
        const int j  = q & 7;
        const int lr = (q >> 3) & 15;
        const int kq = (q >> 7) & 3;
        const int ks = (q >> 9) % 9;
        const int gnt = q / 4608;
        const int n  = gnt * 16 + lr;
        const int kn = ks * 32 + kq * 8 + j;
        const int ko = kn < 128 ? kn : (kn < 160 ? kn + 128 : kn - 32);
        const float w = Wmsg[(size_t)tt * CAT * AD + (size_t)ko * AD + n];
        const unsigned int hi = f2bf(w);
        const float r = w - __uint_as_float(hi << 16);
        const size_t o = (size_t)tt * (CAT * AD) + q;
        Wt_hi[o] = (ushort_t)hi;
        Wt_lo[o] = (ushort_t)f2bf(r);
    } else {
        const int id = (b - AGG_B - ESUM_B - CW_B) * 256 + threadIdx.x;  // < 196608
        const int t   = id / 98304;
        const int rem = id % 98304;
        const int mat = rem / 49152;
        const int q   = rem % 49152;
        const int nt = q / 2048,  r1 = q % 2048;
        const int ks = r1 / 512,  r2 = r1 % 512;
        const int kq = r2 / 128,  r3 = r2 % 128;
        const int lr = r3 / 8,    j  = r3 % 8;
        const int wv = nt / 6, within = nt % 6;
        const int gate = within % 3, hf = within / 3;
        const int n = gate * 128 + wv * 32 + hf * 16 + lr;   // permuted column
        const int k = ks * 32 + kq * 8 + j;
        const float* W = mat ? W_hh : W_ih;
        const float w = W[(size_t)t * ND * G3 + (size_t)k * G3 + n];
        const unsigned int hi = f2bf(w);
        const float res = w - __uint_as_float(hi << 16);
        const size_t o = (size_t)t * 49152 + q;
        if (mat) { Bhh_hi[o] = (ushort_t)hi; Bhh_lo[o] = (ushort_t)f2bf(res); }
        else     { Bih_hi[o] = (ushort_t)hi; Bih_lo[o] = (ushort_t)f2bf(res); }
    }
}

// ---------------------------------------------------------------------------
// Fused msg+GRU, M=32 per block. EXACT Round-6 kernel (proven 69.5 us,
// 68 VGPR, no spill): Round-3 structure + s_setprio(1) around MFMA clusters.
// Lesson ledger: (256,4) -> 64-VGPR cap -> spill (R5, 138us);
//                (256,2)+M=64 -> needs ~200 VGPR -> spill (R4, 118us);
//                (256,3) -> 68-76 VGPR natural fit (R3/R6). Do not touch.
// ---------------------------------------------------------------------------
__global__ __launch_bounds__(256, 3) void fused_msg_gru_kernel(
    const ushort_t* __restrict__ S_hi, const ushort_t* __restrict__ S_lo,
    const float* __restrict__ h_cur, const float* __restrict__ E,
    const int* __restrict__ rowptr,
    const ushort_t* __restrict__ Wt_hi, const ushort_t* __restrict__ Wt_lo,
    const float* __restrict__ bmsg,
    const ushort_t* __restrict__ Bih_hi, const ushort_t* __restrict__ Bih_lo,
    const ushort_t* __restrict__ Bhh_hi, const ushort_t* __restrict__ Bhh_lo,
    const float* __restrict__ b_ih, const float* __restrict__ b_hh,
    float* __restrict__ h_out)
{
    __shared__ __align__(16) char smem[37888];
    ushort_t* xh    = (ushort_t*)smem;           // [32][168] = 10752 B
    ushort_t* xl    = xh + 32 * XP2;             // [32][168] = 10752 B
    ushort_t* sh_hi = xl + 32 * XP2;             // [32][128] swz = 8192 B
    ushort_t* sh_lo = sh_hi + 32 * 128;          // [32][128] swz = 8192 B
    // phase C/D: sa aliases xh/xl region (16384 <= 21504)
    ushort_t* sa_hi = (ushort_t*)smem;           // [32][128] swz
    ushort_t* sa_lo = sa_hi + 32 * 128;
    __shared__ float sdeg[32];

    const int t    = threadIdx.x;
    const int wave = t >> 6;
    const int lane = t & 63;
    const int kq   = lane >> 4;
    const int lr   = lane & 15;
    const int n0   = blockIdx.x * 32;

    const float mbias0 = bmsg[wave * 32 + lr];
    const float mbias1 = bmsg[wave * 32 + 16 + lr];

    // ---- phase A: stage X=[S|E] and h ----
    {
        const int row = t >> 3, c8 = t & 7;
        const int n = min(n0 + row, N_NODES - 1);
        if (t < 32) {
            const int nn = min(n0 + t, N_NODES - 1);
            sdeg[t] = (float)(rowptr[nn + 1] - rowptr[nn]);
        }
        // S: pre-split copies -> X cols 0..127
        {
            const uint4* ph = (const uint4*)(S_hi + (size_t)n * ND + c8 * 16);
            const uint4* pl = (const uint4*)(S_lo + (size_t)n * ND + c8 * 16);
            *(uint4*)&xh[row * XP2 + c8 * 16]     = ph[0];
            *(uint4*)&xh[row * XP2 + c8 * 16 + 8] = ph[1];
            *(uint4*)&xl[row * XP2 + c8 * 16]     = pl[0];
            *(uint4*)&xl[row * XP2 + c8 * 16 + 8] = pl[1];
        }
        // h: split into swizzled sh (serves both Wd-msg term and GRU)
        {
            const float4* hp = (const float4*)(h_cur + (size_t)n * ND + c8 * 16);
            const float4 v0 = hp[0], v1 = hp[1], v2 = hp[2], v3 = hp[3];
            uint4 h0, h1, l0, l1;
            split2(v0.x, v0.y, h0.x, l0.x); split2(v0.z, v0.w, h0.y, l0.y);
            split2(v1.x, v1.y, h0.z, l0.z); split2(v1.z, v1.w, h0.w, l0.w);
            split2(v2.x, v2.y, h1.x, l1.x); split2(v2.z, v2.w, h1.y, l1.y);
            split2(v3.x, v3.y, h1.z, l1.z); split2(v3.z, v3.w, h1.w, l1.w);
            const int so  = (row * 128 + c8 * 16)     ^ ((row & 7) << 3);
            const int so2 = (row * 128 + c8 * 16 + 8) ^ ((row & 7) << 3);
            *(uint4*)(sh_hi + so)  = h0;  *(uint4*)(sh_hi + so2) = h1;
            *(uint4*)(sh_lo + so)  = l0;  *(uint4*)(sh_lo + so2) = l1;
        }
        // E -> X cols 128..159
        {
            const float4 e4 = *(const float4*)(E + (size_t)n * ED + c8 * 4);
            uint2 h0, l0;
            split2(e4.x, e4.y, h0.x, l0.x); split2(e4.z, e4.w, h0.y, l0.y);
            *(uint2*)&xh[row * XP2 + 128 + c8 * 4] = h0;
            *(uint2*)&xl[row * XP2 + 128 + c8 * 4] = l0;
        }
    }
    __syncthreads();

    // ---- phase B: aX = X@W[Ws|We] (ks 0..4), aP = h@Wd (ks 5..8) ----
    f32x4 aX00 = {0.f,0.f,0.f,0.f}, aX01 = {0.f,0.f,0.f,0.f};
    f32x4 aX10 = {0.f,0.f,0.f,0.f}, aX11 = {0.f,0.f,0.f,0.f};
    f32x4 aP00 = {0.f,0.f,0.f,0.f}, aP01 = {0.f,0.f,0.f,0.f};
    f32x4 aP10 = {0.f,0.f,0.f,0.f}, aP11 = {0.f,0.f,0.f,0.f};
    {
        const size_t wb0 = (size_t)(wave * 2 + 0) * 4608 + kq * 128 + lr * 8;
        const size_t wb1 = (size_t)(wave * 2 + 1) * 4608 + kq * 128 + lr * 8;
        const ushort_t* wh0 = Wt_hi + wb0;  const ushort_t* wl0 = Wt_lo + wb0;
        const ushort_t* wh1 = Wt_hi + wb1;  const ushort_t* wl1 = Wt_lo + wb1;
        #pragma unroll
        for (int ks = 0; ks < 5; ++ks) {
            const int ko = ks * 32 + kq * 8;
            const bfrag a0h = *(const bfrag*)&xh[lr * XP2 + ko];
            const bfrag a0l = *(const bfrag*)&xl[lr * XP2 + ko];
            const bfrag a1h = *(const bfrag*)&xh[(16 + lr) * XP2 + ko];
            const bfrag a1l = *(const bfrag*)&xl[(16 + lr) * XP2 + ko];
            const bfrag b0h = *(const bfrag*)(wh0 + ks * 512);
            const bfrag b0l = *(const bfrag*)(wl0 + ks * 512);
            const bfrag b1h = *(const bfrag*)(wh1 + ks * 512);
            const bfrag b1l = *(const bfrag*)(wl1 + ks * 512);
            __builtin_amdgcn_s_setprio(1);
            aX00 = __builtin_amdgcn_mfma_f32_16x16x32_bf16(a0h, b0h, aX00, 0, 0, 0);
            aX00 = __builtin_amdgcn_mfma_f32_16x16x32_bf16(a0l, b0h, aX00, 0, 0, 0);
            aX00 = __builtin_amdgcn_mfma_f32_16x16x32_bf16(a0h, b0l, aX00, 0, 0, 0);
            aX01 = __builtin_amdgcn_mfma_f32_16x16x32_bf16(a0h, b1h, aX01, 0, 0, 0);
            aX01 = __builtin_amdgcn_mfma_f32_16x16x32_bf16(a0l, b1h, aX01, 0, 0, 0);
            aX01 = __builtin_amdgcn_mfma_f32_16x16x32_bf16(a0h, b1l, aX01, 0, 0, 0);
            aX10 = __builtin_amdgcn_mfma_f32_16x16x32_bf16(a1h, b0h, aX10, 0, 0, 0);
            aX10 = __builtin_amdgcn_mfma_f32_16x16x32_bf16(a1l, b0h, aX10, 0, 0, 0);
            aX10 = __builtin_amdgcn_mfma_f32_16x16x32_bf16(a1h, b0l, aX10, 0, 0, 0);
            aX11 = __builtin_amdgcn_mfma_f32_16x16x32_bf16(a1h, b1h, aX11, 0, 0, 0);
            aX11 = __builtin_amdgcn_mfma_f32_16x16x32_bf16(a1l, b1h, aX11, 0, 0, 0);
            aX11 = __builtin_amdgcn_mfma_f32_16x16x32_bf16(a1h, b1l, aX11, 0, 0, 0);
            __builtin_amdgcn_s_setprio(0);
        }
        #pragma unroll
        for (int ks = 5; ks < 9; ++ks) {
            const int hk = (ks - 5) * 32 + kq * 8;
            const int o0 = (lr * 128 + hk)        ^ ((lr & 7) << 3);
            const int o1 = ((16 + lr) * 128 + hk) ^ ((lr & 7) << 3);
            const bfrag a0h = *(const bfrag*)(sh_hi + o0);
            const bfrag a0l = *(const bfrag*)(sh_lo + o0);
            const bfrag a1h = *(const bfrag*)(sh_hi + o1);
            const bfrag a1l = *(const bfrag*)(sh_lo + o1);
            const bfrag b0h = *(const bfrag*)(wh0 + ks * 512);
            const bfrag b0l = *(const bfrag*)(wl0 + ks * 512);
            const bfrag b1h = *(const bfrag*)(wh1 + ks * 512);
            const bfrag b1l = *(const bfrag*)(wl1 + ks * 512);
            __builtin_amdgcn_s_setprio(1);
            aP00 = __builtin_amdgcn_mfma_f32_16x16x32_bf16(a0h, b0h, aP00, 0, 0, 0);
            aP00 = __builtin_amdgcn_mfma_f32_16x16x32_bf16(a0l, b0h, aP00, 0, 0, 0);
            aP00 = __builtin_amdgcn_mfma_f32_16x16x32_bf16(a0h, b0l, aP00, 0, 0, 0);
            aP01 = __builtin_amdgcn_mfma_f32_16x16x32_bf16(a0h, b1h, aP01, 0, 0, 0);
            aP01 = __builtin_amdgcn_mfma_f32_16x16x32_bf16(a0l, b1h, aP01, 0, 0, 0);
            aP01 = __builtin_amdgcn_mfma_f32_16x16x32_bf16(a0h, b1l, aP01, 0, 0, 0);
            aP10 = __builtin_amdgcn_mfma_f32_16x16x32_bf16(a1h, b0h, aP10, 0, 0, 0);
            aP10 = __builtin_amdgcn_mfma_f32_16x16x32_bf16(a1l, b0h, aP10, 0, 0, 0);
            aP10 = __builtin_amdgcn_mfma_f32_16x16x32_bf16(a1h, b0l, aP10, 0, 0, 0);
            aP11 = __builtin_amdgcn_mfma_f32_16x16x32_bf16(a1h, b1h, aP11, 0, 0, 0);
            aP11 = __builtin_amdgcn_mfma_f32_16x16x32_bf16(a1l, b1h, aP11, 0, 0, 0);
            aP11 = __builtin_amdgcn_mfma_f32_16x16x32_bf16(a1h, b1l, aP11, 0, 0, 0);
            __builtin_amdgcn_s_setprio(0);
        }
    }
    __syncthreads();   // xh/xl reads complete before aliasing writes

    // ---- phase C: a = aX + deg*(aP + bias) -> split -> swizzled sa ----
    #pragma unroll
    for (int r = 0; r < 4; ++r) {
        const int row0 = kq * 4 + r;
        const int row1 = 16 + row0;
        const int c0 = wave * 32 + lr, c1 = c0 + 16;
        const float d0 = sdeg[row0], d1 = sdeg[row1];
        ushort_t h, l;
        split1(aX00[r] + d0 * (aP00[r] + mbias0), h, l);
        { const int o = (row0 * 128 + c0) ^ ((row0 & 7) << 3); sa_hi[o] = h; sa_lo[o] = l; }
        split1(aX01[r] + d0 * (aP01[r] + mbias1), h, l);
        { const int o = (row0 * 128 + c1) ^ ((row0 & 7) << 3); sa_hi[o] = h; sa_lo[o] = l; }
        split1(aX10[r] + d1 * (aP10[r] + mbias0), h, l);
        { const int o = (row1 * 128 + c0) ^ ((row1 & 7) << 3); sa_hi[o] = h; sa_lo[o] = l; }
        split1(aX11[r] + d1 * (aP11[r] + mbias1), h, l);
        { const int o = (row1 * 128 + c1) ^ ((row1 & 7) << 3); sa_hi[o] = h; sa_lo[o] = l; }
    }
    __syncthreads();

    // ---- phase D+E: two half-passes, gates in-register via permuted cols ----
    #pragma unroll
    for (int half = 0; half < 2; ++half) {
        f32x4 ai[2][3], ah2[2][3];
        #pragma unroll
        for (int m = 0; m < 2; ++m)
            #pragma unroll
            for (int g = 0; g < 3; ++g) {
                ai[m][g]  = (f32x4){0.f, 0.f, 0.f, 0.f};
                ah2[m][g] = (f32x4){0.f, 0.f, 0.f, 0.f};
            }
        #pragma unroll
        for (int ks = 0; ks < 4; ++ks) {
            bfrag afh[2], afl[2], hfh[2], hfl[2];
            #pragma unroll
            for (int m = 0; m < 2; ++m) {
                const int o = ((m * 16 + lr) * 128 + ks * 32 + kq * 8) ^ ((lr & 7) << 3);
                afh[m] = *(const bfrag*)(sa_hi + o);
                afl[m] = *(const bfrag*)(sa_lo + o);
                hfh[m] = *(const bfrag*)(sh_hi + o);
                hfl[m] = *(const bfrag*)(sh_lo + o);
            }
            #pragma unroll
            for (int g = 0; g < 3; ++g) {
                const int gnt = wave * 6 + half * 3 + g;
                const size_t bo = (size_t)(gnt * 2048 + ks * 512 + kq * 128 + lr * 8);
                const bfrag bih_h = *(const bfrag*)(Bih_hi + bo);
                const bfrag bih_l = *(const bfrag*)(Bih_lo + bo);
                const bfrag bhh_h = *(const bfrag*)(Bhh_hi + bo);
                const bfrag bhh_l = *(const bfrag*)(Bhh_lo + bo);
                __builtin_amdgcn_s_setprio(1);
                #pragma unroll
                for (int m = 0; m < 2; ++m) {
                    ai[m][g]  = __builtin_amdgcn_mfma_f32_16x16x32_bf16(afh[m], bih_h, ai[m][g], 0, 0, 0);
                    ai[m][g]  = __builtin_amdgcn_mfma_f32_16x16x32_bf16(afl[m], bih_h, ai[m][g], 0, 0, 0);
                    ai[m][g]  = __builtin_amdgcn_mfma_f32_16x16x32_bf16(afh[m], bih_l, ai[m][g], 0, 0, 0);
                    ah2[m][g] = __builtin_amdgcn_mfma_f32_16x16x32_bf16(hfh[m], bhh_h, ah2[m][g], 0, 0, 0);
                    ah2[m][g] = __builtin_amdgcn_mfma_f32_16x16x32_bf16(hfl[m], bhh_h, ah2[m][g], 0, 0, 0);
                    ah2[m][g] = __builtin_amdgcn_mfma_f32_16x16x32_bf16(hfh[m], bhh_l, ah2[m][g], 0, 0, 0);
                }
                __builtin_amdgcn_s_setprio(0);
            }
        }
        // epilogue for this half: pure registers, exact fp32 h from L2
        const int c = wave * 32 + half * 16 + lr;
        const float br  = b_ih[c] + b_hh[c];
        const float bz  = b_ih[128 + c] + b_hh[128 + c];
        const float bin = b_ih[256 + c];
        const float bhn = b_hh[256 + c];
        #pragma unroll
        for (int m = 0; m < 2; ++m)
            #pragma unroll
            for (int r = 0; r < 4; ++r) {
                const int nn = n0 + m * 16 + kq * 4 + r;
                if (nn < N_NODES) {
                    const float hc = h_cur[(size_t)nn * ND + c];
                    const float rg = 1.f / (1.f + __expf(-(ai[m][0][r] + ah2[m][0][r] + br)));
                    const float zg = 1.f / (1.f + __expf(-(ai[m][1][r] + ah2[m][1][r] + bz)));
                    const float npre = ai[m][2][r] + bin + rg * (ah2[m][2][r] + bhn);
                    const float ng = 1.f - 2.f / (__expf(2.f * npre) + 1.f);   // tanh, overflow-safe
                    h_out[(size_t)nn * ND + c] = (1.f - zg) * ng + zg * hc;
                }
            }
    }
}

// ---------------------------------------------------------------------------
extern "C" void kernel_launch(void* const* d_in, const int* in_sizes, int n_in,
                              void* d_out, int out_size, void* d_ws, size_t ws_size,
                              hipStream_t stream)
{
    const float* hv   = (const float*)d_in[0];
    const float* he   = (const float*)d_in[1];
    const int*   src  = (const int*)d_in[2];
    const int*   dst  = (const int*)d_in[3];
    const float* Wmsg = (const float*)d_in[4];
    const float* bmsg = (const float*)d_in[5];
    const float* Wih  = (const float*)d_in[6];
    const float* Whh  = (const float*)d_in[7];
    const float* bih  = (const float*)d_in[8];
    const float* bhh  = (const float*)d_in[9];
    float* out = (float*)d_out;

    const int nscan = ((N_NODES + SCAN_BS - 1) / SCAN_BS) * SCAN_BS;  // 50176
    const int nblk  = nscan / SCAN_BS;                                // 98

    char* p = (char*)d_ws;
    ushort_t* S_hi = (ushort_t*)p;            p += (size_t)N_NODES * ND * 2;
    ushort_t* S_lo = (ushort_t*)p;            p += (size_t)N_NODES * ND * 2;
    float* E = (float*)p;                     p += (size_t)N_NODES * ED * 4;   // 6.4 MB
    ushort_t* Wt_hi = (ushort_t*)p;           p += (size_t)2 * AD * CAT * 2;
    ushort_t* Wt_lo = (ushort_t*)p;           p += (size_t)2 * AD * CAT * 2;
    ushort_t* Bih_hi = (ushort_t*)p;          p += (size_t)2 * G3 * ND * 2;
    ushort_t* Bih_lo = (ushort_t*)p;          p += (size_t)2 * G3 * ND * 2;
    ushort_t* Bhh_hi = (ushort_t*)p;          p += (size_t)2 * G3 * ND * 2;
    ushort_t* Bhh_lo = (ushort_t*)p;          p += (size_t)2 * G3 * ND * 2;
    int* deg    = (int*)p;                    p += (size_t)nscan * 4;
    int* rowptr = (int*)p;                    p += (size_t)nscan * 4;
    int* rank_  = (int*)p;                    p += (size_t)N_EDGES * 4;
    int* bsum   = (int*)p;                    p += 128 * 4;
    int2* edat  = (int2*)p;                   p += (size_t)N_EDGES * 8;

    // ---- CSR sort chain (fill is atomic-free: rank captured in hist) ----
    hipMemsetAsync(deg, 0, (size_t)nscan * 4, stream);
    hist_kernel<<<(N_EDGES + 255) / 256, 256, 0, stream>>>(dst, deg, rank_);
    scan_block_kernel<<<nblk, SCAN_BS, 0, stream>>>(deg, rowptr, bsum, nscan);
    scan_sums_kernel<<<1, 128, 0, stream>>>(bsum, nblk);
    scan_add_kernel<<<nblk, SCAN_BS, 0, stream>>>(rowptr, bsum, nscan);
    fill_kernel<<<(N_EDGES + 255) / 256, 256, 0, stream>>>(dst, src, rowptr, rank_, edat);

    // ---- merged: agg(t=0) + esum + weight converts (all fill-gated) ----
    aux_kernel<<<AGG_B + ESUM_B + CW_B + CG_B, 256, 0, stream>>>(
        hv, edat, rowptr, S_hi, S_lo,
        he, E,
        Wmsg, Wt_hi, Wt_lo,
        Wih, Whh, Bih_hi, Bih_lo, Bhh_hi, Bhh_lo);

    const int tile_blocks = (N_NODES + 31) / 32;   // 1563

    for (int t = 0; t < 2; ++t) {
        const float* h_cur = (t == 0) ? hv : out;
        if (t == 1)
            agg_kernel<<<(N_NODES + 7) / 8, 256, 0, stream>>>(
                h_cur, edat, rowptr, S_hi, S_lo);
        fused_msg_gru_kernel<<<tile_blocks, 256, 0, stream>>>(
            S_hi, S_lo, h_cur, E, rowptr,
            Wt_hi + (size_t)t * AD * CAT, Wt_lo + (size_t)t * AD * CAT,
            bmsg + (size_t)t * AD,
            Bih_hi + (size_t)t * G3 * ND, Bih_lo + (size_t)t * G3 * ND,
            Bhh_hi + (size_t)t * G3 * ND, Bhh_lo + (size_t)t * G3 * ND,
            bih + (size_t)t * G3, bhh + (size_t)t * G3, out);
    }
}